// Round 3
// baseline (14768.748 us; speedup 1.0000x reference)
//
#include <hip/hip_runtime.h>
#include <hip/hip_bf16.h>
#include <math.h>

#define TT 64
#define FF 32
#define HH 64
#define NN 4      // nodes per block
#define G4 256    // 4*H gate rows
#define GG1 64
#define GG2 32

typedef float f32x4 __attribute__((ext_vector_type(4)));

__device__ __forceinline__ float fexp2(float x){ return __builtin_amdgcn_exp2f(x); }
__device__ __forceinline__ float frcp (float x){ return __builtin_amdgcn_rcpf(x); }
// sigm(v) = 1/(1+2^(-v*log2e)) ; tanh(v) = 1 - 2/(1+2^(2v*log2e))
__device__ __forceinline__ float sigm (float v){ return frcp(1.0f + fexp2(-1.442695041f*v)); }
__device__ __forceinline__ float ftanh(float v){ return fmaf(-2.0f, frcp(1.0f + fexp2(2.885390082f*v)), 1.0f); }

// sum across the 4 lanes of a quad via DPP quad_perm (VALU pipe, no LDS)
__device__ __forceinline__ float quad_reduce(float v){
  int a  = __builtin_bit_cast(int, v);
  int b  = __builtin_amdgcn_update_dpp(0, a, 0xB1, 0xF, 0xF, true);  // xor 1
  float s = v + __builtin_bit_cast(float, b);
  int c  = __builtin_bit_cast(int, s);
  int d  = __builtin_amdgcn_update_dpp(0, c, 0x4E, 0xF, 0xF, true);  // xor 2
  return s + __builtin_bit_cast(float, d);
}

__device__ __forceinline__ float dp4(f32x4 a, f32x4 b, float acc){
  acc = fmaf(a[0], b[0], acc);
  acc = fmaf(a[1], b[1], acc);
  acc = fmaf(a[2], b[2], acc);
  return fmaf(a[3], b[3], acc);
}

// volatile asm load: cannot be rematerialized/sunk into the loop by the compiler
#define GL(dst, base, OFF) \
  asm volatile("global_load_dwordx4 %0, %1, off offset:" OFF : "=v"(dst) : "v"(base))

// ---------------------------------------------------------------------------
// Fused 2-layer LSTM. Block = 512 threads = 128 row-pairs x 4 K-quarters,
// NN=4 nodes per block. Thread (p,q) holds quarter q of weight rows 2p,2p+1
// of all 4 matrices in registers (112 floats, pinned via asm loads).
// Each ds_read_b128 of shared x/h feeds 8 FMAs (2 rows). Quarter-dots are
// combined with DPP quad butterflies. x for all 64 timesteps staged in LDS.
// ---------------------------------------------------------------------------
__global__ __launch_bounds__(512, 2) void lstm_fused(
    const float* __restrict__ x,
    const float* __restrict__ Wih0, const float* __restrict__ Whh0,
    const float* __restrict__ bih0, const float* __restrict__ bhh0,
    const float* __restrict__ Wih1, const float* __restrict__ Whh1,
    const float* __restrict__ bih1, const float* __restrict__ bhh1,
    float* __restrict__ hout, int n)
{
  const int tid = threadIdx.x;
  const int p   = tid >> 2;          // row pair 0..127
  const int q   = tid & 3;           // K-quarter 0..3
  const int r0  = 2*p, r1 = r0 + 1;  // gate rows
  const int nA  = blockIdx.x * NN;

  __shared__ float xls[NN][TT][FF];  // 32 KB: all timesteps of this block's x
  __shared__ float h0s[NN][HH];
  __shared__ float h1s[NN][HH];
  __shared__ float gs [NN][G4];

  // ---- pinned weight loads (28 x dwordx4 = 112 VGPRs) ----
  const float* pWi0 = Wih0 + r0*FF + q*8;
  const float* pWh0 = Whh0 + r0*HH + q*16;
  const float* pWi1 = Wih1 + r0*HH + q*16;
  const float* pWh1 = Whh1 + r0*HH + q*16;
  f32x4 wi0[2][2], wh0[2][4], wi1[2][4], wh1[2][4];
  GL(wi0[0][0], pWi0, "0");   GL(wi0[0][1], pWi0, "16");
  GL(wi0[1][0], pWi0, "128"); GL(wi0[1][1], pWi0, "144");
  GL(wh0[0][0], pWh0, "0");   GL(wh0[0][1], pWh0, "16");
  GL(wh0[0][2], pWh0, "32");  GL(wh0[0][3], pWh0, "48");
  GL(wh0[1][0], pWh0, "256"); GL(wh0[1][1], pWh0, "272");
  GL(wh0[1][2], pWh0, "288"); GL(wh0[1][3], pWh0, "304");
  GL(wi1[0][0], pWi1, "0");   GL(wi1[0][1], pWi1, "16");
  GL(wi1[0][2], pWi1, "32");  GL(wi1[0][3], pWi1, "48");
  GL(wi1[1][0], pWi1, "256"); GL(wi1[1][1], pWi1, "272");
  GL(wi1[1][2], pWi1, "288"); GL(wi1[1][3], pWi1, "304");
  GL(wh1[0][0], pWh1, "0");   GL(wh1[0][1], pWh1, "16");
  GL(wh1[0][2], pWh1, "32");  GL(wh1[0][3], pWh1, "48");
  GL(wh1[1][0], pWh1, "256"); GL(wh1[1][1], pWh1, "272");
  GL(wh1[1][2], pWh1, "288"); GL(wh1[1][3], pWh1, "304");

  // biases for this thread's two rows (tiny, normal loads)
  const float b00 = bih0[r0] + bhh0[r0];
  const float b01 = bih0[r1] + bhh0[r1];
  const float b10 = bih1[r0] + bhh1[r0];
  const float b11 = bih1[r1] + bhh1[r1];

  // stage all x for this block's nodes (contiguous since nodes are adjacent)
  {
    int avail = n - nA; if (avail > NN) avail = NN;
    const f32x4* src = (const f32x4*)(x + (size_t)nA * TT * FF);
    f32x4* dst = (f32x4*)&xls[0][0][0];
    const int total = avail * TT * FF / 4;
    for (int i = tid; i < total; i += 512) dst[i] = src[i];
  }
  if (tid < NN*HH) { (&h0s[0][0])[tid] = 0.0f; (&h1s[0][0])[tid] = 0.0f; }
  float cell0 = 0.0f, cell1 = 0.0f;   // cell state, valid for tid < 256

  asm volatile("s_waitcnt vmcnt(0)" ::: "memory");
  __builtin_amdgcn_sched_barrier(0);
  __syncthreads();

  for (int t = 0; t < TT; ++t) {
    // ---------- layer 0 gates ----------
    float acc0[NN], acc1[NN];
#pragma unroll
    for (int nd = 0; nd < NN; ++nd) {
      const f32x4* xv = (const f32x4*)&xls[nd][t][q*8];
      const f32x4* hv = (const f32x4*)&h0s[nd][q*16];
      f32x4 xa = xv[0], xb = xv[1];
      f32x4 ha = hv[0], hb = hv[1], hc = hv[2], hd = hv[3];
      float s0 = 0.0f, s1 = 0.0f;
      s0 = dp4(xa, wi0[0][0], s0); s1 = dp4(xa, wi0[1][0], s1);
      s0 = dp4(xb, wi0[0][1], s0); s1 = dp4(xb, wi0[1][1], s1);
      s0 = dp4(ha, wh0[0][0], s0); s1 = dp4(ha, wh0[1][0], s1);
      s0 = dp4(hb, wh0[0][1], s0); s1 = dp4(hb, wh0[1][1], s1);
      s0 = dp4(hc, wh0[0][2], s0); s1 = dp4(hc, wh0[1][2], s1);
      s0 = dp4(hd, wh0[0][3], s0); s1 = dp4(hd, wh0[1][3], s1);
      acc0[nd] = s0; acc1[nd] = s1;
    }
#pragma unroll
    for (int nd = 0; nd < NN; ++nd) { acc0[nd] = quad_reduce(acc0[nd]); acc1[nd] = quad_reduce(acc1[nd]); }
    {
      float v0 = acc0[0], v1 = acc1[0];
      if (q == 1) { v0 = acc0[1]; v1 = acc1[1]; }
      if (q == 2) { v0 = acc0[2]; v1 = acc1[2]; }
      if (q == 3) { v0 = acc0[3]; v1 = acc1[3]; }
      *(float2*)&gs[q][r0] = make_float2(v0 + b00, v1 + b01);  // lane q owns node q
    }
    __syncthreads();

    if (tid < NN*HH) {
      const int nd = tid >> 6, m = tid & 63;
      const float gi = gs[nd][m], gf = gs[nd][m+64], gg = gs[nd][m+128], go = gs[nd][m+192];
      cell0 = sigm(gf)*cell0 + sigm(gi)*ftanh(gg);
      h0s[nd][m] = sigm(go)*ftanh(cell0);
    }
    __syncthreads();

    // ---------- layer 1 gates ----------
#pragma unroll
    for (int nd = 0; nd < NN; ++nd) {
      const f32x4* pv = (const f32x4*)&h0s[nd][q*16];
      const f32x4* qv = (const f32x4*)&h1s[nd][q*16];
      f32x4 pa = pv[0], pb = pv[1], pc = pv[2], pd = pv[3];
      f32x4 qa = qv[0], qb = qv[1], qc = qv[2], qd = qv[3];
      float s0 = 0.0f, s1 = 0.0f;
      s0 = dp4(pa, wi1[0][0], s0); s1 = dp4(pa, wi1[1][0], s1);
      s0 = dp4(pb, wi1[0][1], s0); s1 = dp4(pb, wi1[1][1], s1);
      s0 = dp4(pc, wi1[0][2], s0); s1 = dp4(pc, wi1[1][2], s1);
      s0 = dp4(pd, wi1[0][3], s0); s1 = dp4(pd, wi1[1][3], s1);
      s0 = dp4(qa, wh1[0][0], s0); s1 = dp4(qa, wh1[1][0], s1);
      s0 = dp4(qb, wh1[0][1], s0); s1 = dp4(qb, wh1[1][1], s1);
      s0 = dp4(qc, wh1[0][2], s0); s1 = dp4(qc, wh1[1][2], s1);
      s0 = dp4(qd, wh1[0][3], s0); s1 = dp4(qd, wh1[1][3], s1);
      acc0[nd] = s0; acc1[nd] = s1;
    }
#pragma unroll
    for (int nd = 0; nd < NN; ++nd) { acc0[nd] = quad_reduce(acc0[nd]); acc1[nd] = quad_reduce(acc1[nd]); }
    {
      float v0 = acc0[0], v1 = acc1[0];
      if (q == 1) { v0 = acc0[1]; v1 = acc1[1]; }
      if (q == 2) { v0 = acc0[2]; v1 = acc1[2]; }
      if (q == 3) { v0 = acc0[3]; v1 = acc1[3]; }
      *(float2*)&gs[q][r0] = make_float2(v0 + b10, v1 + b11);
    }
    __syncthreads();

    if (tid < NN*HH) {
      const int nd = tid >> 6, m = tid & 63;
      const float gi = gs[nd][m], gf = gs[nd][m+64], gg = gs[nd][m+128], go = gs[nd][m+192];
      cell1 = sigm(gf)*cell1 + sigm(gi)*ftanh(gg);
      h1s[nd][m] = sigm(go)*ftanh(cell1);
    }
    __syncthreads();
  }

  if (tid < NN*HH) {
    const int nd = tid >> 6, m = tid & 63;
    const int node = nA + nd;
    if (node < n) hout[(size_t)node*HH + m] = h1s[nd][m];
  }
}

// ---------------------------------------------------------------------------
// GCN support kernels (unchanged — not the bottleneck)
// ---------------------------------------------------------------------------
__global__ void k_count(const int* __restrict__ dst, int E, int* __restrict__ cnt)
{
  int e = blockIdx.x * blockDim.x + threadIdx.x;
  if (e < E) atomicAdd(&cnt[dst[e]], 1);
}

__global__ void k_scan_build(const int* __restrict__ cnt, int n,
                             int* __restrict__ offs, int* __restrict__ cursor,
                             float* __restrict__ dinv)
{
  __shared__ int part[1024];
  const int tid = threadIdx.x;
  const int per = (n + 1023) >> 10;
  const int base = tid * per;
  int s = 0;
  for (int i = 0; i < per; ++i) { int idx = base + i; if (idx < n) s += cnt[idx]; }
  part[tid] = s;
  __syncthreads();
  for (int off = 1; off < 1024; off <<= 1) {
    int v = 0;
    if (tid >= off) v = part[tid - off];
    __syncthreads();
    part[tid] += v;
    __syncthreads();
  }
  int run = part[tid] - s;
  for (int i = 0; i < per; ++i) {
    int idx = base + i;
    if (idx < n) {
      offs[idx] = run; cursor[idx] = run;
      int c = cnt[idx];
      dinv[idx] = 1.0f / sqrtf((float)(c + 1));
      run += c;
    }
  }
}

__global__ void k_fill(const int* __restrict__ src, const int* __restrict__ dst,
                       int E, int* __restrict__ cursor, int* __restrict__ csr)
{
  int e = blockIdx.x * blockDim.x + threadIdx.x;
  if (e < E) {
    int d = dst[e];
    int pos = atomicAdd(&cursor[d], 1);
    csr[pos] = src[e];
  }
}

template <int K, int M>
__global__ void k_xw(const float* __restrict__ A, const float* __restrict__ W,
                     float* __restrict__ out, int n)
{
  int idx = blockIdx.x * blockDim.x + threadIdx.x;
  int row = idx / M, col = idx % M;
  if (row >= n) return;
  const float* a = A + (size_t)row * K;
  float acc = 0.0f;
#pragma unroll
  for (int k = 0; k < K; ++k) acc = fmaf(a[k], W[k*M + col], acc);
  out[(size_t)row*M + col] = acc;
}

template <int FD>
__global__ void k_agg(const float* __restrict__ xw, const int* __restrict__ offs,
                      const int* __restrict__ cnt, const int* __restrict__ csr,
                      const float* __restrict__ dinv, const float* __restrict__ b,
                      float* __restrict__ out, int n)
{
  int gidx = blockIdx.x * blockDim.x + threadIdx.x;
  int node = gidx / FD, lane = gidx % FD;
  if (node >= n) return;
  const float di = dinv[node];
  float acc = xw[(size_t)node*FD + lane] * di * di;
  const int s0 = offs[node], e0 = s0 + cnt[node];
  for (int p = s0; p < e0; ++p) {
    int s = csr[p];
    acc = fmaf(xw[(size_t)s*FD + lane], dinv[s] * di, acc);
  }
  out[(size_t)node*FD + lane] = fmaxf(acc + b[lane], 0.0f);
}

__global__ void k_fc(const float* __restrict__ g2, const int* __restrict__ sid,
                     const float* __restrict__ fcW, const float* __restrict__ fcb,
                     float* __restrict__ out, int n)
{
  int i = blockIdx.x * blockDim.x + threadIdx.x;
  if (i >= n) return;
  const float* row = g2 + (size_t)sid[i] * GG2;
  float acc = fcb[0];
#pragma unroll
  for (int f = 0; f < GG2; ++f) acc = fmaf(row[f], fcW[f], acc);
  out[i] = acc;
}

// ---------------------------------------------------------------------------
extern "C" void kernel_launch(void* const* d_in, const int* in_sizes, int n_in,
                              void* d_out, int out_size, void* d_ws, size_t ws_size,
                              hipStream_t stream)
{
  const float* x    = (const float*)d_in[0];
  const int*   sid  = (const int*)  d_in[1];
  const int*   eidx = (const int*)  d_in[2];
  const float* Wih0 = (const float*)d_in[3];
  const float* Whh0 = (const float*)d_in[4];
  const float* bih0 = (const float*)d_in[5];
  const float* bhh0 = (const float*)d_in[6];
  const float* Wih1 = (const float*)d_in[7];
  const float* Whh1 = (const float*)d_in[8];
  const float* bih1 = (const float*)d_in[9];
  const float* bhh1 = (const float*)d_in[10];
  const float* g1W  = (const float*)d_in[11];
  const float* g1b  = (const float*)d_in[12];
  const float* g2W  = (const float*)d_in[13];
  const float* g2b  = (const float*)d_in[14];
  const float* fcW  = (const float*)d_in[15];
  const float* fcb  = (const float*)d_in[16];

  const int n = in_sizes[1];
  const int E = in_sizes[2] / 2;
  float* out = (float*)d_out;

  char* w = (char*)d_ws;
  auto carve = [&](size_t bytes) -> void* {
    void* p = (void*)w; w += (bytes + 255) & ~(size_t)255; return p;
  };
  float* hfin   = (float*)carve((size_t)n * HH * 4);
  int*   cnt    = (int*)  carve((size_t)n * 4);
  int*   offs   = (int*)  carve((size_t)n * 4);
  int*   cursor = (int*)  carve((size_t)n * 4);
  float* dinv   = (float*)carve((size_t)n * 4);
  int*   csr    = (int*)  carve((size_t)E * 4);
  float* xw1    = (float*)carve((size_t)n * GG1 * 4);
  float* g1     = (float*)carve((size_t)n * GG1 * 4);
  float* xw2    = (float*)carve((size_t)n * GG2 * 4);
  float* g2     = (float*)carve((size_t)n * GG2 * 4);

  const int* src = eidx;
  const int* dst = eidx + E;

  lstm_fused<<<(n + NN - 1) / NN, 512, 0, stream>>>(x, Wih0, Whh0, bih0, bhh0,
                                                    Wih1, Whh1, bih1, bhh1, hfin, n);

  hipMemsetAsync(cnt, 0, (size_t)n * 4, stream);
  k_count<<<(E + 255) / 256, 256, 0, stream>>>(dst, E, cnt);
  k_scan_build<<<1, 1024, 0, stream>>>(cnt, n, offs, cursor, dinv);
  k_fill<<<(E + 255) / 256, 256, 0, stream>>>(src, dst, E, cursor, csr);

  k_xw<HH, GG1><<<((size_t)n * GG1 + 255) / 256, 256, 0, stream>>>(hfin, g1W, xw1, n);
  k_agg<GG1><<<((size_t)n * GG1 + 255) / 256, 256, 0, stream>>>(xw1, offs, cnt, csr, dinv, g1b, g1, n);

  k_xw<GG1, GG2><<<((size_t)n * GG2 + 255) / 256, 256, 0, stream>>>(g1, g2W, xw2, n);
  k_agg<GG2><<<((size_t)n * GG2 + 255) / 256, 256, 0, stream>>>(xw2, offs, cnt, csr, dinv, g2b, g2, n);

  k_fc<<<(n + 255) / 256, 256, 0, stream>>>(g2, sid, fcW, fcb, out, n);
}

// Round 4
// 3046.824 us; speedup vs baseline: 4.8473x; 4.8473x over previous
//
#include <hip/hip_runtime.h>
#include <math.h>

#define TT 64
#define FF 32
#define HH 64
#define NN 8      // nodes per block
#define G4 256    // 4*H gate rows
#define GG1 64
#define GG2 32

typedef float f32x4 __attribute__((ext_vector_type(4)));

__device__ __forceinline__ float fexp2(float x){ return __builtin_amdgcn_exp2f(x); }
__device__ __forceinline__ float frcp (float x){ return __builtin_amdgcn_rcpf(x); }
// sigm(v) = 1/(1+2^(-v*log2e)) ; tanh(v) = 1 - 2/(1+2^(2v*log2e))
__device__ __forceinline__ float sigm (float v){ return frcp(1.0f + fexp2(-1.442695041f*v)); }
__device__ __forceinline__ float ftanh(float v){ return fmaf(-2.0f, frcp(1.0f + fexp2(2.885390082f*v)), 1.0f); }

// sum across the 4 lanes of a quad via DPP quad_perm (VALU pipe, no LDS)
__device__ __forceinline__ float quad_reduce(float v){
  int a  = __builtin_bit_cast(int, v);
  int b  = __builtin_amdgcn_update_dpp(0, a, 0xB1, 0xF, 0xF, true);  // quad swap 1
  float s = v + __builtin_bit_cast(float, b);
  int c  = __builtin_bit_cast(int, s);
  int d  = __builtin_amdgcn_update_dpp(0, c, 0x4E, 0xF, 0xF, true);  // quad swap 2
  return s + __builtin_bit_cast(float, d);
}

__device__ __forceinline__ float dp4(f32x4 a, f32x4 b, float acc){
  acc = fmaf(a[0], b[0], acc);
  acc = fmaf(a[1], b[1], acc);
  acc = fmaf(a[2], b[2], acc);
  return fmaf(a[3], b[3], acc);
}

// compile-time-indexed 4-way select (no dynamic register-array indexing)
__device__ __forceinline__ float sel4(float a0, float a1, float a2, float a3, int q){
  float x = (q & 1) ? a1 : a0;
  float y = (q & 1) ? a3 : a2;
  return (q & 2) ? y : x;
}

// zero-cost pin: value becomes opaque to remat; with pressure < budget it stays in regs
#define PIN(v) asm volatile("" : "+v"(v))

// ---------------------------------------------------------------------------
// Fused 2-layer LSTM. Block = 1024 threads = 256 gate rows x 4 K-quarters,
// NN=8 nodes per block. Thread (r,q) holds quarter q of row r of all 4 weight
// matrices: 56 floats -> total ~100 VGPR, under the 128 budget that a
// 1024-thread block (4 waves/EU) imposes. amdgpu_waves_per_eu(4,4) pins the
// allocator budget to exactly 128 so it neither remats (round-2 bug) nor
// spills (round-3 bug). Zero weight duplication within a block.
// ---------------------------------------------------------------------------
__global__ __launch_bounds__(1024)
__attribute__((amdgpu_waves_per_eu(4, 4)))
void lstm_fused(
    const float* __restrict__ x,
    const float* __restrict__ Wih0, const float* __restrict__ Whh0,
    const float* __restrict__ bih0, const float* __restrict__ bhh0,
    const float* __restrict__ Wih1, const float* __restrict__ Whh1,
    const float* __restrict__ bih1, const float* __restrict__ bhh1,
    float* __restrict__ hout, int n)
{
  const int tid = threadIdx.x;
  const int r   = tid >> 2;     // gate row 0..255
  const int q   = tid & 3;      // K-quarter 0..3
  const int nA  = blockIdx.x * NN;

  __shared__ float xls[NN][TT][FF];   // 64 KB: all timesteps of this block's x
  __shared__ float h0s[NN][HH];
  __shared__ float h1s[NN][HH];
  __shared__ float gs [NN][G4];

  // ---- weight quarter-rows -> registers (14 quads = 56 VGPRs) ----
  f32x4 wi0[2], wh0[4], wi1[4], wh1[4];
  {
    const f32x4* a = (const f32x4*)&Wih0[r*FF + q*8];
    wi0[0] = a[0]; wi0[1] = a[1];
    const f32x4* b = (const f32x4*)&Whh0[r*HH + q*16];
    wh0[0] = b[0]; wh0[1] = b[1]; wh0[2] = b[2]; wh0[3] = b[3];
    const f32x4* c = (const f32x4*)&Wih1[r*HH + q*16];
    wi1[0] = c[0]; wi1[1] = c[1]; wi1[2] = c[2]; wi1[3] = c[3];
    const f32x4* d = (const f32x4*)&Whh1[r*HH + q*16];
    wh1[0] = d[0]; wh1[1] = d[1]; wh1[2] = d[2]; wh1[3] = d[3];
  }
  float b0 = bih0[r] + bhh0[r];
  float b1 = bih1[r] + bhh1[r];

  // stage all x for this block's nodes (contiguous global reads)
  {
    int avail = n - nA; if (avail > NN) avail = NN;
    const f32x4* src = (const f32x4*)(x + (size_t)nA * TT * FF);
    f32x4* dst = (f32x4*)&xls[0][0][0];
    const int total = avail * TT * FF / 4;
    for (int i = tid; i < total; i += 1024) dst[i] = src[i];
  }
  if (tid < NN*HH) { (&h0s[0][0])[tid] = 0.0f; (&h1s[0][0])[tid] = 0.0f; }
  float cell0 = 0.0f, cell1 = 0.0f;   // cell state of (nd,m)=(tid>>6,tid&63), tid<512

  PIN(wi0[0]); PIN(wi0[1]);
  PIN(wh0[0]); PIN(wh0[1]); PIN(wh0[2]); PIN(wh0[3]);
  PIN(wi1[0]); PIN(wi1[1]); PIN(wi1[2]); PIN(wi1[3]);
  PIN(wh1[0]); PIN(wh1[1]); PIN(wh1[2]); PIN(wh1[3]);
  PIN(b0); PIN(b1);
  __syncthreads();

  float a[NN];
  for (int t = 0; t < TT; ++t) {
    // ---------- layer 0: gate row r, quarter q, nodes 0..7 ----------
#pragma unroll
    for (int nd = 0; nd < NN; ++nd) {
      const f32x4* xv = (const f32x4*)&xls[nd][t][q*8];
      const f32x4* hv = (const f32x4*)&h0s[nd][q*16];
      float s = 0.0f;
      { f32x4 v0 = xv[0], v1 = xv[1]; s = dp4(v0, wi0[0], s); s = dp4(v1, wi0[1], s); }
      { f32x4 v0 = hv[0], v1 = hv[1]; s = dp4(v0, wh0[0], s); s = dp4(v1, wh0[1], s); }
      { f32x4 v0 = hv[2], v1 = hv[3]; s = dp4(v0, wh0[2], s); s = dp4(v1, wh0[3], s); }
      a[nd] = s;
    }
#pragma unroll
    for (int nd = 0; nd < NN; ++nd) a[nd] = quad_reduce(a[nd]);
    {
      float u = sel4(a[0], a[1], a[2], a[3], q) + b0;   // lane q owns node q
      float v = sel4(a[4], a[5], a[6], a[7], q) + b0;   // and node q+4
      gs[q    ][r] = u;
      gs[q + 4][r] = v;
    }
    __syncthreads();

    if (tid < NN*HH) {
      const int nd = tid >> 6, m = tid & 63;
      const float gi = gs[nd][m], gf = gs[nd][m+64], gg = gs[nd][m+128], go = gs[nd][m+192];
      cell0 = sigm(gf)*cell0 + sigm(gi)*ftanh(gg);
      h0s[nd][m] = sigm(go)*ftanh(cell0);
    }
    __syncthreads();

    // ---------- layer 1 ----------
#pragma unroll
    for (int nd = 0; nd < NN; ++nd) {
      const f32x4* pv = (const f32x4*)&h0s[nd][q*16];
      const f32x4* qv = (const f32x4*)&h1s[nd][q*16];
      float s = 0.0f;
      { f32x4 v0 = pv[0], v1 = pv[1]; s = dp4(v0, wi1[0], s); s = dp4(v1, wi1[1], s); }
      { f32x4 v0 = pv[2], v1 = pv[3]; s = dp4(v0, wi1[2], s); s = dp4(v1, wi1[3], s); }
      { f32x4 v0 = qv[0], v1 = qv[1]; s = dp4(v0, wh1[0], s); s = dp4(v1, wh1[1], s); }
      { f32x4 v0 = qv[2], v1 = qv[3]; s = dp4(v0, wh1[2], s); s = dp4(v1, wh1[3], s); }
      a[nd] = s;
    }
#pragma unroll
    for (int nd = 0; nd < NN; ++nd) a[nd] = quad_reduce(a[nd]);
    {
      float u = sel4(a[0], a[1], a[2], a[3], q) + b1;
      float v = sel4(a[4], a[5], a[6], a[7], q) + b1;
      gs[q    ][r] = u;
      gs[q + 4][r] = v;
    }
    __syncthreads();

    if (tid < NN*HH) {
      const int nd = tid >> 6, m = tid & 63;
      const float gi = gs[nd][m], gf = gs[nd][m+64], gg = gs[nd][m+128], go = gs[nd][m+192];
      cell1 = sigm(gf)*cell1 + sigm(gi)*ftanh(gg);
      h1s[nd][m] = sigm(go)*ftanh(cell1);
    }
    __syncthreads();
  }

  if (tid < NN*HH) {
    const int nd = tid >> 6, m = tid & 63;
    const int node = nA + nd;
    if (node < n) hout[(size_t)node*HH + m] = h1s[nd][m];
  }
}

// ---------------------------------------------------------------------------
// GCN support kernels (unchanged — not the bottleneck)
// ---------------------------------------------------------------------------
__global__ void k_count(const int* __restrict__ dst, int E, int* __restrict__ cnt)
{
  int e = blockIdx.x * blockDim.x + threadIdx.x;
  if (e < E) atomicAdd(&cnt[dst[e]], 1);
}

__global__ void k_scan_build(const int* __restrict__ cnt, int n,
                             int* __restrict__ offs, int* __restrict__ cursor,
                             float* __restrict__ dinv)
{
  __shared__ int part[1024];
  const int tid = threadIdx.x;
  const int per = (n + 1023) >> 10;
  const int base = tid * per;
  int s = 0;
  for (int i = 0; i < per; ++i) { int idx = base + i; if (idx < n) s += cnt[idx]; }
  part[tid] = s;
  __syncthreads();
  for (int off = 1; off < 1024; off <<= 1) {
    int v = 0;
    if (tid >= off) v = part[tid - off];
    __syncthreads();
    part[tid] += v;
    __syncthreads();
  }
  int run = part[tid] - s;
  for (int i = 0; i < per; ++i) {
    int idx = base + i;
    if (idx < n) {
      offs[idx] = run; cursor[idx] = run;
      int c = cnt[idx];
      dinv[idx] = 1.0f / sqrtf((float)(c + 1));
      run += c;
    }
  }
}

__global__ void k_fill(const int* __restrict__ src, const int* __restrict__ dst,
                       int E, int* __restrict__ cursor, int* __restrict__ csr)
{
  int e = blockIdx.x * blockDim.x + threadIdx.x;
  if (e < E) {
    int d = dst[e];
    int pos = atomicAdd(&cursor[d], 1);
    csr[pos] = src[e];
  }
}

template <int K, int M>
__global__ void k_xw(const float* __restrict__ A, const float* __restrict__ W,
                     float* __restrict__ out, int n)
{
  int idx = blockIdx.x * blockDim.x + threadIdx.x;
  int row = idx / M, col = idx % M;
  if (row >= n) return;
  const float* a = A + (size_t)row * K;
  float acc = 0.0f;
#pragma unroll
  for (int k = 0; k < K; ++k) acc = fmaf(a[k], W[k*M + col], acc);
  out[(size_t)row*M + col] = acc;
}

template <int FD>
__global__ void k_agg(const float* __restrict__ xw, const int* __restrict__ offs,
                      const int* __restrict__ cnt, const int* __restrict__ csr,
                      const float* __restrict__ dinv, const float* __restrict__ b,
                      float* __restrict__ out, int n)
{
  int gidx = blockIdx.x * blockDim.x + threadIdx.x;
  int node = gidx / FD, lane = gidx % FD;
  if (node >= n) return;
  const float di = dinv[node];
  float acc = xw[(size_t)node*FD + lane] * di * di;
  const int s0 = offs[node], e0 = s0 + cnt[node];
  for (int p = s0; p < e0; ++p) {
    int s = csr[p];
    acc = fmaf(xw[(size_t)s*FD + lane], dinv[s] * di, acc);
  }
  out[(size_t)node*FD + lane] = fmaxf(acc + b[lane], 0.0f);
}

__global__ void k_fc(const float* __restrict__ g2, const int* __restrict__ sid,
                     const float* __restrict__ fcW, const float* __restrict__ fcb,
                     float* __restrict__ out, int n)
{
  int i = blockIdx.x * blockDim.x + threadIdx.x;
  if (i >= n) return;
  const float* row = g2 + (size_t)sid[i] * GG2;
  float acc = fcb[0];
#pragma unroll
  for (int f = 0; f < GG2; ++f) acc = fmaf(row[f], fcW[f], acc);
  out[i] = acc;
}

// ---------------------------------------------------------------------------
extern "C" void kernel_launch(void* const* d_in, const int* in_sizes, int n_in,
                              void* d_out, int out_size, void* d_ws, size_t ws_size,
                              hipStream_t stream)
{
  const float* x    = (const float*)d_in[0];
  const int*   sid  = (const int*)  d_in[1];
  const int*   eidx = (const int*)  d_in[2];
  const float* Wih0 = (const float*)d_in[3];
  const float* Whh0 = (const float*)d_in[4];
  const float* bih0 = (const float*)d_in[5];
  const float* bhh0 = (const float*)d_in[6];
  const float* Wih1 = (const float*)d_in[7];
  const float* Whh1 = (const float*)d_in[8];
  const float* bih1 = (const float*)d_in[9];
  const float* bhh1 = (const float*)d_in[10];
  const float* g1W  = (const float*)d_in[11];
  const float* g1b  = (const float*)d_in[12];
  const float* g2W  = (const float*)d_in[13];
  const float* g2b  = (const float*)d_in[14];
  const float* fcW  = (const float*)d_in[15];
  const float* fcb  = (const float*)d_in[16];

  const int n = in_sizes[1];
  const int E = in_sizes[2] / 2;
  float* out = (float*)d_out;

  char* w = (char*)d_ws;
  auto carve = [&](size_t bytes) -> void* {
    void* p = (void*)w; w += (bytes + 255) & ~(size_t)255; return p;
  };
  float* hfin   = (float*)carve((size_t)n * HH * 4);
  int*   cnt    = (int*)  carve((size_t)n * 4);
  int*   offs   = (int*)  carve((size_t)n * 4);
  int*   cursor = (int*)  carve((size_t)n * 4);
  float* dinv   = (float*)carve((size_t)n * 4);
  int*   csr    = (int*)  carve((size_t)E * 4);
  float* xw1    = (float*)carve((size_t)n * GG1 * 4);
  float* g1     = (float*)carve((size_t)n * GG1 * 4);
  float* xw2    = (float*)carve((size_t)n * GG2 * 4);
  float* g2     = (float*)carve((size_t)n * GG2 * 4);

  const int* src = eidx;
  const int* dst = eidx + E;

  lstm_fused<<<(n + NN - 1) / NN, 1024, 0, stream>>>(x, Wih0, Whh0, bih0, bhh0,
                                                     Wih1, Whh1, bih1, bhh1, hfin, n);

  hipMemsetAsync(cnt, 0, (size_t)n * 4, stream);
  k_count<<<(E + 255) / 256, 256, 0, stream>>>(dst, E, cnt);
  k_scan_build<<<1, 1024, 0, stream>>>(cnt, n, offs, cursor, dinv);
  k_fill<<<(E + 255) / 256, 256, 0, stream>>>(src, dst, E, cursor, csr);

  k_xw<HH, GG1><<<((size_t)n * GG1 + 255) / 256, 256, 0, stream>>>(hfin, g1W, xw1, n);
  k_agg<GG1><<<((size_t)n * GG1 + 255) / 256, 256, 0, stream>>>(xw1, offs, cnt, csr, dinv, g1b, g1, n);

  k_xw<GG1, GG2><<<((size_t)n * GG2 + 255) / 256, 256, 0, stream>>>(g1, g2W, xw2, n);
  k_agg<GG2><<<((size_t)n * GG2 + 255) / 256, 256, 0, stream>>>(xw2, offs, cnt, csr, dinv, g2b, g2, n);

  k_fc<<<(n + 255) / 256, 256, 0, stream>>>(g2, sid, fcW, fcb, out, n);
}